// Round 8
// baseline (131.091 us; speedup 1.0000x reference)
//
#include <hip/hip_runtime.h>

#define LN_EPS 1e-5f
#define C_M 256
#define C_Z 128
#define NO_BINS 15
#define MAX_PH 64

typedef float f4 __attribute__((ext_vector_type(4)));

__device__ __forceinline__ f4 f4zero() { f4 t = {0.f, 0.f, 0.f, 0.f}; return t; }

// one-hot bin index (or -1); strict inequalities; numpy f32 op order (no FMA)
__device__ __forceinline__ signed char bin_calc(const float* __restrict__ x,
                                                int i, int j)
{
    const float dx = x[3 * i + 0] - x[3 * j + 0];
    const float dy = x[3 * i + 1] - x[3 * j + 1];
    const float dz = x[3 * i + 2] - x[3 * j + 2];
    const float d = __fadd_rn(__fadd_rn(__fmul_rn(dx, dx), __fmul_rn(dy, dy)),
                              __fmul_rn(dz, dz));
    int cnt = 0;
#pragma unroll
    for (int k = 0; k < NO_BINS; ++k) {
        const float bk = 3.25f + 1.25f * (float)k;
        cnt += (d > bk * bk) ? 1 : 0;
    }
    bool valid = (cnt > 0) && (d < 1e8f);
    if (valid && cnt < NO_BINS) {
        // boundary equality d == sq[cnt] zeroes the one-hot (strict ineq.)
        const float bc = 3.25f + 1.25f * (float)cnt;
        valid = (d != bc * bc);
    }
    return valid ? (signed char)(cnt - 1) : (signed char)(-1);
}

__device__ __forceinline__ void ln_stats(const f4 v, float& s, float& s2)
{
    s  = v.x + v.y + v.z + v.w;
    s2 = v.x * v.x + v.y * v.y + v.z * v.z + v.w * v.w;
}

// compute + store one 4-row phase (rows already in registers)
__device__ __forceinline__ void phase_out(
    f4 v0, f4 v1, f4 v2, f4 v3,
    const signed char* binss, int p, int half, const float* lw,
    const f4 wv, const f4 bv, float* __restrict__ out_z,
    long long r, long long S, int lane)
{
    const int b0 = (int)binss[(p + 0) * 8 + half];   // broadcast LDS byte
    const int b1 = (int)binss[(p + 1) * 8 + half];
    const int b2 = (int)binss[(p + 2) * 8 + half];
    const int b3 = (int)binss[(p + 3) * 8 + half];

    f4 e0 = f4zero(), e1 = f4zero(), e2 = f4zero(), e3 = f4zero();
    if (b0 >= 0) e0 = reinterpret_cast<const f4*>(lw + b0 * C_Z)[lane];
    if (b1 >= 0) e1 = reinterpret_cast<const f4*>(lw + b1 * C_Z)[lane];
    if (b2 >= 0) e2 = reinterpret_cast<const f4*>(lw + b2 * C_Z)[lane];
    if (b3 >= 0) e3 = reinterpret_cast<const f4*>(lw + b3 * C_Z)[lane];

    float s0, q0, s1, q1, s2, q2, s3, q3;
    ln_stats(v0, s0, q0); ln_stats(v1, s1, q1);
    ln_stats(v2, s2, q2); ln_stats(v3, s3, q3);
#pragma unroll
    for (int msk = 1; msk < 32; msk <<= 1) {   // stays within the 32-lane group
        s0 += __shfl_xor(s0, msk); q0 += __shfl_xor(q0, msk);
        s1 += __shfl_xor(s1, msk); q1 += __shfl_xor(q1, msk);
        s2 += __shfl_xor(s2, msk); q2 += __shfl_xor(q2, msk);
        s3 += __shfl_xor(s3, msk); q3 += __shfl_xor(q3, msk);
    }
    const float mu0 = s0 * (1.0f / C_Z), iv0 = rsqrtf(q0 * (1.0f / C_Z) - mu0 * mu0 + LN_EPS);
    const float mu1 = s1 * (1.0f / C_Z), iv1 = rsqrtf(q1 * (1.0f / C_Z) - mu1 * mu1 + LN_EPS);
    const float mu2 = s2 * (1.0f / C_Z), iv2 = rsqrtf(q2 * (1.0f / C_Z) - mu2 * mu2 + LN_EPS);
    const float mu3 = s3 * (1.0f / C_Z), iv3 = rsqrtf(q3 * (1.0f / C_Z) - mu3 * mu3 + LN_EPS);

    f4 o0 = (v0 - mu0) * iv0 * wv + bv + e0;
    f4 o1 = (v1 - mu1) * iv1 * wv + bv + e1;
    f4 o2 = (v2 - mu2) * iv2 * wv + bv + e2;
    f4 o3 = (v3 - mu3) * iv3 * wv + bv + e3;
    __builtin_nontemporal_store(o0, reinterpret_cast<f4*>(out_z + r * C_Z) + lane);
    __builtin_nontemporal_store(o1, reinterpret_cast<f4*>(out_z + (r + S) * C_Z) + lane);
    __builtin_nontemporal_store(o2, reinterpret_cast<f4*>(out_z + (r + 2 * S) * C_Z) + lane);
    __builtin_nontemporal_store(o3, reinterpret_cast<f4*>(out_z + (r + 3 * S) * C_Z) + lane);
}

// ---- fused kernel: grid = 2N blocks, j slot-constant, bins in LDS,
//      one-phase load rotation so stores never gate the next phase ----
__global__ __launch_bounds__(256, 6) void fused_rot(
    const float* __restrict__ m, const float* __restrict__ ln_m_w,
    const float* __restrict__ ln_m_b, float* __restrict__ out_m, int m_rows,
    const float* __restrict__ z, const float* __restrict__ x,
    const float* __restrict__ lin_w, const float* __restrict__ lin_b,
    const float* __restrict__ ln_z_w, const float* __restrict__ ln_z_b,
    float* __restrict__ out_z, int N, int phases)
{
    __shared__ float lw[NO_BINS * C_Z];          // transposed: [bin][c]
    __shared__ signed char binss[MAX_PH * 8];    // [t][half]
    const int tid = threadIdx.x;
    for (int t = tid; t < NO_BINS * C_Z; t += 256) {
        const int c = t / NO_BINS;
        const int bin = t - c * NO_BINS;
        lw[bin * C_Z + c] = lin_w[t];
    }
    // per-block bins: idx = t*8 + h, parallel over all threads (~2 each)
    for (int idx = tid; idx < phases * 8; idx += 256) {
        const int h = idx & 7;
        const int t = idx >> 3;
        const int slot = (int)blockIdx.x * 8 + h;
        const int bi0 = slot / N;
        const int bj  = slot - bi0 * N;
        binss[idx] = bin_calc(x, bi0 + 16 * t, bj);
    }
    __syncthreads();

    // ---- m LayerNorm: first ceil(m_rows/4) blocks, one wave per row ----
    if ((int)blockIdx.x < ((m_rows + 3) >> 2)) {
        const int wid    = tid >> 6;
        const int lane64 = tid & 63;
        const int row    = blockIdx.x * 4 + wid;
        if (row < m_rows) {
            const f4 v = reinterpret_cast<const f4*>(m + (long long)row * C_M)[lane64];
            float s, s2; ln_stats(v, s, s2);
#pragma unroll
            for (int msk = 1; msk < 64; msk <<= 1) {
                s  += __shfl_xor(s,  msk);
                s2 += __shfl_xor(s2, msk);
            }
            const float mu  = s * (1.0f / C_M);
            const float inv = rsqrtf(s2 * (1.0f / C_M) - mu * mu + LN_EPS);
            const f4 wv = reinterpret_cast<const f4*>(ln_m_w)[lane64];
            const f4 bv = reinterpret_cast<const f4*>(ln_m_b)[lane64];
            f4 o = (v - mu) * inv * wv + bv;
            reinterpret_cast<f4*>(out_m + (long long)row * C_M)[lane64] = o;
        }
    }

    // ---- z loop ----
    const int half = tid >> 5;
    const int lane = tid & 31;

    const f4 wv = reinterpret_cast<const f4*>(ln_z_w)[lane];
    f4 bv = reinterpret_cast<const f4*>(ln_z_b)[lane];
    bv += reinterpret_cast<const f4*>(lin_b)[lane];   // fold lin_b

    const int slot = (int)blockIdx.x * 8 + half;      // [0, 16N)
    const long long S = (long long)N * 16;            // rows per phase

    long long r = slot;
    // prologue: phase-0 rows
    f4 a0 = reinterpret_cast<const f4*>(z + r * C_Z)[lane];
    f4 a1 = reinterpret_cast<const f4*>(z + (r + S) * C_Z)[lane];
    f4 a2 = reinterpret_cast<const f4*>(z + (r + 2 * S) * C_Z)[lane];
    f4 a3 = reinterpret_cast<const f4*>(z + (r + 3 * S) * C_Z)[lane];

    int p = 0;
    for (; p < phases - 4; p += 4) {
        const long long rn = r + 4 * S;
        // prefetch next phase BEFORE this phase's stores enter the queue
        const f4 n0 = reinterpret_cast<const f4*>(z + rn * C_Z)[lane];
        const f4 n1 = reinterpret_cast<const f4*>(z + (rn + S) * C_Z)[lane];
        const f4 n2 = reinterpret_cast<const f4*>(z + (rn + 2 * S) * C_Z)[lane];
        const f4 n3 = reinterpret_cast<const f4*>(z + (rn + 3 * S) * C_Z)[lane];
        __builtin_amdgcn_sched_barrier(0);   // pin loads above compute+stores

        phase_out(a0, a1, a2, a3, binss, p, half, lw, wv, bv, out_z, r, S, lane);

        a0 = n0; a1 = n1; a2 = n2; a3 = n3;
        r = rn;
    }
    // epilogue: last phase
    phase_out(a0, a1, a2, a3, binss, p, half, lw, wv, bv, out_z, r, S, lane);
}

// ---- generic fallback (any N) ----
__device__ __forceinline__ int bin_of(const float* __restrict__ x,
                                      const float* sqb, int i, int j)
{
    const float dx = x[3 * i + 0] - x[3 * j + 0];
    const float dy = x[3 * i + 1] - x[3 * j + 1];
    const float dz = x[3 * i + 2] - x[3 * j + 2];
    const float d = __fadd_rn(__fadd_rn(__fmul_rn(dx, dx), __fmul_rn(dy, dy)),
                              __fmul_rn(dz, dz));
    int cnt = 0;
#pragma unroll
    for (int k = 0; k < NO_BINS; ++k) {
        const float bk = 3.25f + 1.25f * (float)k;
        cnt += (d > bk * bk) ? 1 : 0;
    }
    return ((cnt > 0) && (d < 1e8f) && (d != sqb[cnt])) ? cnt - 1 : -1;
}

__global__ __launch_bounds__(256) void fused_generic(
    const float* __restrict__ m, const float* __restrict__ ln_m_w,
    const float* __restrict__ ln_m_b, float* __restrict__ out_m, int m_rows,
    const float* __restrict__ z, const float* __restrict__ x,
    const float* __restrict__ lin_w, const float* __restrict__ lin_b,
    const float* __restrict__ ln_z_w, const float* __restrict__ ln_z_b,
    float* __restrict__ out_z, int N)
{
    __shared__ float lw[NO_BINS * C_Z];
    __shared__ float sqb[16];
    const int tid = threadIdx.x;
    for (int t = tid; t < NO_BINS * C_Z; t += 256) {
        const int c = t / NO_BINS;
        const int bin = t - c * NO_BINS;
        lw[bin * C_Z + c] = lin_w[t];
    }
    if (tid < 16) {
        const float bk = 3.25f + 1.25f * (float)tid;
        sqb[tid] = (tid < NO_BINS) ? bk * bk : -1.0f;
    }
    __syncthreads();

    if ((int)blockIdx.x < ((m_rows + 3) >> 2)) {
        const int wid    = tid >> 6;
        const int lane64 = tid & 63;
        const int row    = blockIdx.x * 4 + wid;
        if (row < m_rows) {
            const f4 v = reinterpret_cast<const f4*>(m + (long long)row * C_M)[lane64];
            float s, s2; ln_stats(v, s, s2);
#pragma unroll
            for (int msk = 1; msk < 64; msk <<= 1) {
                s  += __shfl_xor(s,  msk);
                s2 += __shfl_xor(s2, msk);
            }
            const float mu  = s * (1.0f / C_M);
            const float inv = rsqrtf(s2 * (1.0f / C_M) - mu * mu + LN_EPS);
            const f4 wv = reinterpret_cast<const f4*>(ln_m_w)[lane64];
            const f4 bv = reinterpret_cast<const f4*>(ln_m_b)[lane64];
            f4 o = (v - mu) * inv * wv + bv;
            reinterpret_cast<f4*>(out_m + (long long)row * C_M)[lane64] = o;
        }
    }

    const int half = tid >> 5;
    const int lane = tid & 31;
    const f4 wv = reinterpret_cast<const f4*>(ln_z_w)[lane];
    f4 bv = reinterpret_cast<const f4*>(ln_z_b)[lane];
    bv += reinterpret_cast<const f4*>(lin_b)[lane];

    const long long total  = (long long)N * N;
    const long long stride = (long long)gridDim.x * 8;
    for (long long r = (long long)blockIdx.x * 8 + half; r < total; r += stride) {
        const int i = (int)(r / N);
        const int j = (int)(r - (long long)i * N);
        const f4 v = reinterpret_cast<const f4*>(z + r * C_Z)[lane];
        const int bin = bin_of(x, sqb, i, j);
        f4 e = f4zero();
        if (bin >= 0) e = reinterpret_cast<const f4*>(lw + bin * C_Z)[lane];
        float s, s2; ln_stats(v, s, s2);
#pragma unroll
        for (int msk = 1; msk < 32; msk <<= 1) {
            s  += __shfl_xor(s,  msk);
            s2 += __shfl_xor(s2, msk);
        }
        const float mu  = s * (1.0f / C_Z);
        const float inv = rsqrtf(s2 * (1.0f / C_Z) - mu * mu + LN_EPS);
        f4 o = (v - mu) * inv * wv + bv + e;
        __builtin_nontemporal_store(o, reinterpret_cast<f4*>(out_z + r * C_Z) + lane);
    }
}

extern "C" void kernel_launch(void* const* d_in, const int* in_sizes, int n_in,
                              void* d_out, int out_size, void* d_ws, size_t ws_size,
                              hipStream_t stream) {
    const float* m      = (const float*)d_in[0];
    const float* z      = (const float*)d_in[1];
    const float* x      = (const float*)d_in[2];
    // d_in[3] = seqs (unused)
    const float* lin_w  = (const float*)d_in[4];
    const float* lin_b  = (const float*)d_in[5];
    const float* ln_m_w = (const float*)d_in[6];
    const float* ln_m_b = (const float*)d_in[7];
    const float* ln_z_w = (const float*)d_in[8];
    const float* ln_z_b = (const float*)d_in[9];

    const int N = in_sizes[0] / C_M;          // 768
    float* out_m = (float*)d_out;
    float* out_z = out_m + (long long)N * C_M;

    const int mB = (N + 3) / 4;
    const int phases = N / 16;                // rows per slot

    if ((N % 16) == 0 && phases <= MAX_PH && (phases % 4) == 0 && 2 * N >= mB) {
        // grid = 2N blocks (6/CU at N=768, co-resident), j slot-constant
        fused_rot<<<2 * N, 256, 0, stream>>>(m, ln_m_w, ln_m_b, out_m, N,
                                             z, x, lin_w, lin_b, ln_z_w, ln_z_b,
                                             out_z, N, phases);
    } else {
        int g = 2048;
        if (g < mB) g = mB;
        fused_generic<<<g, 256, 0, stream>>>(m, ln_m_w, ln_m_b, out_m, N,
                                             z, x, lin_w, lin_b, ln_z_w, ln_z_b,
                                             out_z, N);
    }
}

// Round 9
// 106.245 us; speedup vs baseline: 1.2339x; 1.2339x over previous
//
#include <hip/hip_runtime.h>

#define LN_EPS 1e-5f
#define C_M 256
#define C_Z 128
#define NO_BINS 15
#define MAX_PH 64

typedef float f4 __attribute__((ext_vector_type(4)));

__device__ __forceinline__ f4 f4zero() { f4 t = {0.f, 0.f, 0.f, 0.f}; return t; }

// one-hot bin index (or -1); strict inequalities; numpy f32 op order (no FMA)
__device__ __forceinline__ signed char bin_calc(const float* __restrict__ x,
                                                int i, int j)
{
    const float dx = x[3 * i + 0] - x[3 * j + 0];
    const float dy = x[3 * i + 1] - x[3 * j + 1];
    const float dz = x[3 * i + 2] - x[3 * j + 2];
    const float d = __fadd_rn(__fadd_rn(__fmul_rn(dx, dx), __fmul_rn(dy, dy)),
                              __fmul_rn(dz, dz));
    int cnt = 0;
#pragma unroll
    for (int k = 0; k < NO_BINS; ++k) {
        const float bk = 3.25f + 1.25f * (float)k;
        cnt += (d > bk * bk) ? 1 : 0;
    }
    bool valid = (cnt > 0) && (d < 1e8f);
    if (valid && cnt < NO_BINS) {
        // boundary equality d == sq[cnt] zeroes the one-hot (strict ineq.)
        const float bc = 3.25f + 1.25f * (float)cnt;
        valid = (d != bc * bc);
    }
    return valid ? (signed char)(cnt - 1) : (signed char)(-1);
}

__device__ __forceinline__ void ln_stats(const f4 v, float& s, float& s2)
{
    s  = v.x + v.y + v.z + v.w;
    s2 = v.x * v.x + v.y * v.y + v.z * v.z + v.w * v.w;
}

// ---- fused kernel: grid = 2N blocks, j slot-constant, bins in LDS,
//      6-row phases (R7 shape, wider) ----
__global__ __launch_bounds__(256, 6) void fused_w6(
    const float* __restrict__ m, const float* __restrict__ ln_m_w,
    const float* __restrict__ ln_m_b, float* __restrict__ out_m, int m_rows,
    const float* __restrict__ z, const float* __restrict__ x,
    const float* __restrict__ lin_w, const float* __restrict__ lin_b,
    const float* __restrict__ ln_z_w, const float* __restrict__ ln_z_b,
    float* __restrict__ out_z, int N, int phases)
{
    __shared__ float lw[NO_BINS * C_Z];          // transposed: [bin][c]
    __shared__ signed char binss[MAX_PH * 8];    // [t][half]
    const int tid = threadIdx.x;
    for (int t = tid; t < NO_BINS * C_Z; t += 256) {
        const int c = t / NO_BINS;
        const int bin = t - c * NO_BINS;
        lw[bin * C_Z + c] = lin_w[t];
    }
    // per-block bins: idx = t*8 + h, parallel over all threads (~2 each)
    for (int idx = tid; idx < phases * 8; idx += 256) {
        const int h = idx & 7;
        const int t = idx >> 3;
        const int slot = (int)blockIdx.x * 8 + h;
        const int bi0 = slot / N;
        const int bj  = slot - bi0 * N;
        binss[idx] = bin_calc(x, bi0 + 16 * t, bj);
    }
    __syncthreads();

    // ---- m LayerNorm: first ceil(m_rows/4) blocks, one wave per row ----
    if ((int)blockIdx.x < ((m_rows + 3) >> 2)) {
        const int wid    = tid >> 6;
        const int lane64 = tid & 63;
        const int row    = blockIdx.x * 4 + wid;
        if (row < m_rows) {
            const f4 v = reinterpret_cast<const f4*>(m + (long long)row * C_M)[lane64];
            float s, s2; ln_stats(v, s, s2);
#pragma unroll
            for (int msk = 1; msk < 64; msk <<= 1) {
                s  += __shfl_xor(s,  msk);
                s2 += __shfl_xor(s2, msk);
            }
            const float mu  = s * (1.0f / C_M);
            const float inv = rsqrtf(s2 * (1.0f / C_M) - mu * mu + LN_EPS);
            const f4 wv = reinterpret_cast<const f4*>(ln_m_w)[lane64];
            const f4 bv = reinterpret_cast<const f4*>(ln_m_b)[lane64];
            f4 o = (v - mu) * inv * wv + bv;
            reinterpret_cast<f4*>(out_m + (long long)row * C_M)[lane64] = o;
        }
    }

    // ---- z loop: 6-row phases; loads top, stores bottom, nothing else ----
    const int half = tid >> 5;
    const int lane = tid & 31;

    const f4 wv = reinterpret_cast<const f4*>(ln_z_w)[lane];
    f4 bv = reinterpret_cast<const f4*>(ln_z_b)[lane];
    bv += reinterpret_cast<const f4*>(lin_b)[lane];   // fold lin_b

    const int slot = (int)blockIdx.x * 8 + half;      // [0, 16N)
    const long long S = (long long)N * 16;            // rows per phase

    long long r = slot;
    for (int p = 0; p < phases; p += 6) {
        const long long r0 = r,         r1 = r + S,     r2 = r + 2 * S;
        const long long r3 = r + 3 * S, r4 = r + 4 * S, r5 = r + 5 * S;

        const f4 v0 = reinterpret_cast<const f4*>(z + r0 * C_Z)[lane];
        const f4 v1 = reinterpret_cast<const f4*>(z + r1 * C_Z)[lane];
        const f4 v2 = reinterpret_cast<const f4*>(z + r2 * C_Z)[lane];
        const f4 v3 = reinterpret_cast<const f4*>(z + r3 * C_Z)[lane];
        const f4 v4 = reinterpret_cast<const f4*>(z + r4 * C_Z)[lane];
        const f4 v5 = reinterpret_cast<const f4*>(z + r5 * C_Z)[lane];

        const int b0 = (int)binss[(p + 0) * 8 + half];   // broadcast LDS byte
        const int b1 = (int)binss[(p + 1) * 8 + half];
        const int b2 = (int)binss[(p + 2) * 8 + half];
        const int b3 = (int)binss[(p + 3) * 8 + half];
        const int b4 = (int)binss[(p + 4) * 8 + half];
        const int b5 = (int)binss[(p + 5) * 8 + half];

        f4 e0 = f4zero(), e1 = f4zero(), e2 = f4zero();
        f4 e3 = f4zero(), e4 = f4zero(), e5 = f4zero();
        if (b0 >= 0) e0 = reinterpret_cast<const f4*>(lw + b0 * C_Z)[lane];
        if (b1 >= 0) e1 = reinterpret_cast<const f4*>(lw + b1 * C_Z)[lane];
        if (b2 >= 0) e2 = reinterpret_cast<const f4*>(lw + b2 * C_Z)[lane];
        if (b3 >= 0) e3 = reinterpret_cast<const f4*>(lw + b3 * C_Z)[lane];
        if (b4 >= 0) e4 = reinterpret_cast<const f4*>(lw + b4 * C_Z)[lane];
        if (b5 >= 0) e5 = reinterpret_cast<const f4*>(lw + b5 * C_Z)[lane];

        float s0, q0, s1, q1, s2, q2, s3, q3, s4, q4, s5, q5;
        ln_stats(v0, s0, q0); ln_stats(v1, s1, q1); ln_stats(v2, s2, q2);
        ln_stats(v3, s3, q3); ln_stats(v4, s4, q4); ln_stats(v5, s5, q5);
#pragma unroll
        for (int msk = 1; msk < 32; msk <<= 1) {   // stays within 32-lane group
            s0 += __shfl_xor(s0, msk); q0 += __shfl_xor(q0, msk);
            s1 += __shfl_xor(s1, msk); q1 += __shfl_xor(q1, msk);
            s2 += __shfl_xor(s2, msk); q2 += __shfl_xor(q2, msk);
            s3 += __shfl_xor(s3, msk); q3 += __shfl_xor(q3, msk);
            s4 += __shfl_xor(s4, msk); q4 += __shfl_xor(q4, msk);
            s5 += __shfl_xor(s5, msk); q5 += __shfl_xor(q5, msk);
        }
        const float mu0 = s0 * (1.0f / C_Z), iv0 = rsqrtf(q0 * (1.0f / C_Z) - mu0 * mu0 + LN_EPS);
        const float mu1 = s1 * (1.0f / C_Z), iv1 = rsqrtf(q1 * (1.0f / C_Z) - mu1 * mu1 + LN_EPS);
        const float mu2 = s2 * (1.0f / C_Z), iv2 = rsqrtf(q2 * (1.0f / C_Z) - mu2 * mu2 + LN_EPS);
        const float mu3 = s3 * (1.0f / C_Z), iv3 = rsqrtf(q3 * (1.0f / C_Z) - mu3 * mu3 + LN_EPS);
        const float mu4 = s4 * (1.0f / C_Z), iv4 = rsqrtf(q4 * (1.0f / C_Z) - mu4 * mu4 + LN_EPS);
        const float mu5 = s5 * (1.0f / C_Z), iv5 = rsqrtf(q5 * (1.0f / C_Z) - mu5 * mu5 + LN_EPS);

        f4 o0 = (v0 - mu0) * iv0 * wv + bv + e0;
        f4 o1 = (v1 - mu1) * iv1 * wv + bv + e1;
        f4 o2 = (v2 - mu2) * iv2 * wv + bv + e2;
        f4 o3 = (v3 - mu3) * iv3 * wv + bv + e3;
        f4 o4 = (v4 - mu4) * iv4 * wv + bv + e4;
        f4 o5 = (v5 - mu5) * iv5 * wv + bv + e5;
        __builtin_nontemporal_store(o0, reinterpret_cast<f4*>(out_z + r0 * C_Z) + lane);
        __builtin_nontemporal_store(o1, reinterpret_cast<f4*>(out_z + r1 * C_Z) + lane);
        __builtin_nontemporal_store(o2, reinterpret_cast<f4*>(out_z + r2 * C_Z) + lane);
        __builtin_nontemporal_store(o3, reinterpret_cast<f4*>(out_z + r3 * C_Z) + lane);
        __builtin_nontemporal_store(o4, reinterpret_cast<f4*>(out_z + r4 * C_Z) + lane);
        __builtin_nontemporal_store(o5, reinterpret_cast<f4*>(out_z + r5 * C_Z) + lane);

        r += 6 * S;
    }
}

// ---- generic fallback (any N) ----
__device__ __forceinline__ int bin_of(const float* __restrict__ x,
                                      const float* sqb, int i, int j)
{
    const float dx = x[3 * i + 0] - x[3 * j + 0];
    const float dy = x[3 * i + 1] - x[3 * j + 1];
    const float dz = x[3 * i + 2] - x[3 * j + 2];
    const float d = __fadd_rn(__fadd_rn(__fmul_rn(dx, dx), __fmul_rn(dy, dy)),
                              __fmul_rn(dz, dz));
    int cnt = 0;
#pragma unroll
    for (int k = 0; k < NO_BINS; ++k) {
        const float bk = 3.25f + 1.25f * (float)k;
        cnt += (d > bk * bk) ? 1 : 0;
    }
    return ((cnt > 0) && (d < 1e8f) && (d != sqb[cnt])) ? cnt - 1 : -1;
}

__global__ __launch_bounds__(256) void fused_generic(
    const float* __restrict__ m, const float* __restrict__ ln_m_w,
    const float* __restrict__ ln_m_b, float* __restrict__ out_m, int m_rows,
    const float* __restrict__ z, const float* __restrict__ x,
    const float* __restrict__ lin_w, const float* __restrict__ lin_b,
    const float* __restrict__ ln_z_w, const float* __restrict__ ln_z_b,
    float* __restrict__ out_z, int N)
{
    __shared__ float lw[NO_BINS * C_Z];
    __shared__ float sqb[16];
    const int tid = threadIdx.x;
    for (int t = tid; t < NO_BINS * C_Z; t += 256) {
        const int c = t / NO_BINS;
        const int bin = t - c * NO_BINS;
        lw[bin * C_Z + c] = lin_w[t];
    }
    if (tid < 16) {
        const float bk = 3.25f + 1.25f * (float)tid;
        sqb[tid] = (tid < NO_BINS) ? bk * bk : -1.0f;
    }
    __syncthreads();

    if ((int)blockIdx.x < ((m_rows + 3) >> 2)) {
        const int wid    = tid >> 6;
        const int lane64 = tid & 63;
        const int row    = blockIdx.x * 4 + wid;
        if (row < m_rows) {
            const f4 v = reinterpret_cast<const f4*>(m + (long long)row * C_M)[lane64];
            float s, s2; ln_stats(v, s, s2);
#pragma unroll
            for (int msk = 1; msk < 64; msk <<= 1) {
                s  += __shfl_xor(s,  msk);
                s2 += __shfl_xor(s2, msk);
            }
            const float mu  = s * (1.0f / C_M);
            const float inv = rsqrtf(s2 * (1.0f / C_M) - mu * mu + LN_EPS);
            const f4 wv = reinterpret_cast<const f4*>(ln_m_w)[lane64];
            const f4 bv = reinterpret_cast<const f4*>(ln_m_b)[lane64];
            f4 o = (v - mu) * inv * wv + bv;
            reinterpret_cast<f4*>(out_m + (long long)row * C_M)[lane64] = o;
        }
    }

    const int half = tid >> 5;
    const int lane = tid & 31;
    const f4 wv = reinterpret_cast<const f4*>(ln_z_w)[lane];
    f4 bv = reinterpret_cast<const f4*>(ln_z_b)[lane];
    bv += reinterpret_cast<const f4*>(lin_b)[lane];

    const long long total  = (long long)N * N;
    const long long stride = (long long)gridDim.x * 8;
    for (long long r = (long long)blockIdx.x * 8 + half; r < total; r += stride) {
        const int i = (int)(r / N);
        const int j = (int)(r - (long long)i * N);
        const f4 v = reinterpret_cast<const f4*>(z + r * C_Z)[lane];
        const int bin = bin_of(x, sqb, i, j);
        f4 e = f4zero();
        if (bin >= 0) e = reinterpret_cast<const f4*>(lw + bin * C_Z)[lane];
        float s, s2; ln_stats(v, s, s2);
#pragma unroll
        for (int msk = 1; msk < 32; msk <<= 1) {
            s  += __shfl_xor(s,  msk);
            s2 += __shfl_xor(s2, msk);
        }
        const float mu  = s * (1.0f / C_Z);
        const float inv = rsqrtf(s2 * (1.0f / C_Z) - mu * mu + LN_EPS);
        f4 o = (v - mu) * inv * wv + bv + e;
        __builtin_nontemporal_store(o, reinterpret_cast<f4*>(out_z + r * C_Z) + lane);
    }
}

extern "C" void kernel_launch(void* const* d_in, const int* in_sizes, int n_in,
                              void* d_out, int out_size, void* d_ws, size_t ws_size,
                              hipStream_t stream) {
    const float* m      = (const float*)d_in[0];
    const float* z      = (const float*)d_in[1];
    const float* x      = (const float*)d_in[2];
    // d_in[3] = seqs (unused)
    const float* lin_w  = (const float*)d_in[4];
    const float* lin_b  = (const float*)d_in[5];
    const float* ln_m_w = (const float*)d_in[6];
    const float* ln_m_b = (const float*)d_in[7];
    const float* ln_z_w = (const float*)d_in[8];
    const float* ln_z_b = (const float*)d_in[9];

    const int N = in_sizes[0] / C_M;          // 768
    float* out_m = (float*)d_out;
    float* out_z = out_m + (long long)N * C_M;

    const int mB = (N + 3) / 4;
    const int phases = N / 16;                // rows per slot (48 at N=768)

    if ((N % 16) == 0 && phases <= MAX_PH && (phases % 6) == 0 && 2 * N >= mB) {
        // grid = 2N blocks (6/CU at N=768, co-resident), j slot-constant
        fused_w6<<<2 * N, 256, 0, stream>>>(m, ln_m_w, ln_m_b, out_m, N,
                                            z, x, lin_w, lin_b, ln_z_w, ln_z_b,
                                            out_z, N, phases);
    } else {
        int g = 2048;
        if (g < mB) g = mB;
        fused_generic<<<g, 256, 0, stream>>>(m, ln_m_w, ln_m_b, out_m, N,
                                             z, x, lin_w, lin_b, ln_z_w, ln_z_b,
                                             out_z, N);
    }
}